// Round 12
// baseline (140.135 us; speedup 1.0000x reference)
//
#include <hip/hip_runtime.h>

#define NN 4096
#define NE 65536
#define ND 64

// ---------- workspace layout (bytes) ----------
// 0      : map    i32[NN]
// 16384  : rem    i32[NN]
// 32768  : relab  i32[NN]
// 49152  : perma  i32[NN]
// 65536  : nkeep  i32
// 65600  : rl     i32[NN]   (len | self<<16, K5)
// 81984  : rowst  i32[NN+1]
// 98432  : key    u32[NN]
// 114816 : incsr  u16[NE]   (128K; KB builds, K5 sorts rows in place)

// ---- KB: CSR build on ONE block (count+scan+scatter in LDS, coalesced dump) ----
// Replaces memset(cnt)+k1count+k2+k3 (4 dispatches -> 1; saves ~3 gaps).
// This is the r0 monolith's phases 1-3, which were fast (LDS atomics, 1 CU).
__global__ void __launch_bounds__(1024) kB_csr(const int* __restrict__ ei,
                                               unsigned short* __restrict__ incsr_g,
                                               int* __restrict__ rowst_g) {
    __shared__ __align__(16) char buf[147520];
    unsigned short* incsr = (unsigned short*)buf;          // 128K
    int* cursor = (int*)(buf + 131072);                    // 16K
    int* wt = (int*)(buf + 147456);                        // 64B
    int tid = threadIdx.x, lane = tid & 63, wv = tid >> 6;

    // phase 1: in-degree count (LDS atomics)
    for (int n = tid; n < NN; n += 1024) cursor[n] = 0;
    __syncthreads();
    const int4* eid4 = (const int4*)(ei + NE);
    for (int i = tid; i < NE / 4; i += 1024) {
        int4 q = eid4[i];
        atomicAdd(&cursor[q.x], 1);
        atomicAdd(&cursor[q.y], 1);
        atomicAdd(&cursor[q.z], 1);
        atomicAdd(&cursor[q.w], 1);
    }
    __syncthreads();

    // phase 2: exclusive prefix scan; persist row starts to global
    int t0 = cursor[4 * tid], t1 = cursor[4 * tid + 1];
    int t2 = cursor[4 * tid + 2], t3 = cursor[4 * tid + 3];
    int tot = t0 + t1 + t2 + t3;
    int inc = tot;
    for (int off = 1; off < 64; off <<= 1) {
        int v = __shfl_up(inc, off);
        if (lane >= off) inc += v;
    }
    if (lane == 63) wt[wv] = inc;
    __syncthreads();
    if (wv == 0 && lane < 16) {
        int v = wt[lane];
        for (int off = 1; off < 16; off <<= 1) {
            int u2 = __shfl_up(v, off);
            if (lane >= off) v += u2;
        }
        wt[lane] = v;
    }
    __syncthreads();
    int waveoff = (wv > 0) ? wt[wv - 1] : 0;
    int excl = waveoff + inc - tot;
    int4 rsv;
    rsv.x = excl; rsv.y = excl + t0; rsv.z = excl + t0 + t1; rsv.w = excl + t0 + t1 + t2;
    ((int4*)rowst_g)[tid] = rsv;
    if (tid == 1023) rowst_g[NN] = NE;
    cursor[4 * tid]     = rsv.x;
    cursor[4 * tid + 1] = rsv.y;
    cursor[4 * tid + 2] = rsv.z;
    cursor[4 * tid + 3] = rsv.w;
    __syncthreads();

    // phase 3: scatter in-edges (row = dst, entry = src node id)
    const int4* eis4 = (const int4*)ei;
    for (int i = tid; i < NE / 4; i += 1024) {
        int4 s = eis4[i];
        int4 d = eid4[i];
        incsr[atomicAdd(&cursor[d.x], 1)] = (unsigned short)s.x;
        incsr[atomicAdd(&cursor[d.y], 1)] = (unsigned short)s.y;
        incsr[atomicAdd(&cursor[d.z], 1)] = (unsigned short)s.z;
        incsr[atomicAdd(&cursor[d.w], 1)] = (unsigned short)s.w;
    }
    __syncthreads();

    // coalesced dump LDS -> global
    for (int i = tid; i < 8192; i += 1024)
        ((int4*)incsr_g)[i] = ((const int4*)incsr)[i];
}

// ---- KX: fused dots+agg+key, one wave per row (replaces k1-dots + k4) ----
// key_v = mono(tanhf(f32( sum_j [ (sum_u x[u][j]) * wrel_j + x[v][j] * wroot_j ] + b )))
// Lane j accumulates agg_j over in-neighbors via coalesced 256B x-row loads;
// entries preloaded per-lane + __shfl broadcast => no dependent-address chain.
// f64 intermediates (as all passing rounds): summation-order-robust under f32 tanh.
__global__ void kX_keys(const float* __restrict__ x, const float* __restrict__ wrel,
                        const float* __restrict__ wroot, const float* __restrict__ bptr,
                        const int* __restrict__ rowst, const unsigned short* __restrict__ incsr,
                        unsigned* __restrict__ key) {
    int gt = blockIdx.x * blockDim.x + threadIdx.x;
    int v = gt >> 6, lane = gt & 63;
    int rs = rowst[v], deg = rowst[v + 1] - rs;
    double acc = 0.0;
    for (int base = 0; base < deg; base += 64) {
        int n = deg - base; if (n > 64) n = 64;
        int ent = (lane < n) ? (int)incsr[rs + base + lane] : 0;
        for (int e = 0; e < n; ++e) {
            int u = __shfl(ent, e);
            acc += (double)x[(u << 6) | lane];
        }
    }
    double red = acc * (double)wrel[lane]
               + (double)x[(v << 6) | lane] * (double)wroot[lane];
    for (int off = 32; off > 0; off >>= 1) red += __shfl_down(red, off);
    if (lane == 0) {
        float sc = tanhf((float)(red + (double)bptr[0]));   // f32 saturation => ref ties
        unsigned m = __float_as_uint(sc);
        m = (m & 0x80000000u) ? ~m : (m | 0x80000000u);     // monotone ascending in score
        key[v] = m;
    }
}

// ------- K5: per-row filter + 64-lane bitonic sort; side job: out-zero -------
__global__ void k5_filtersort(const int* __restrict__ rowst, const unsigned* __restrict__ key,
                              unsigned short* __restrict__ incsr, int* __restrict__ rl,
                              float* __restrict__ out) {
    // side job: zero x_pooled region of out (replaces a memset dispatch; proven r7-r11)
    int g = blockIdx.x * blockDim.x + threadIdx.x;
    if (g < (NN * ND) / 4) ((float4*)out)[g] = make_float4(0.f, 0.f, 0.f, 0.f);

    int v = g >> 6, l = g & 63;
    int rs = rowst[v], deg = rowst[v + 1] - rs;
    unsigned mv = key[v];
    if (deg <= 64) {
        int u = (l < deg) ? (int)incsr[rs + l] : -1;
        bool isself = (l < deg) && (u == v);
        unsigned mu = (l < deg && !isself) ? key[u] : 0u;
        bool keep = (l < deg) && !isself && (mu > mv || (mu == mv && u < v));
        unsigned long long val = keep
            ? ((((unsigned long long)(~mu)) << 12) | (unsigned)u) : ~0ULL;
        int m = __popcll(__ballot(keep));
        bool selfAny = __ballot(isself) != 0ULL;
        // bitonic ascending => row sorted earliest-first
        for (int k = 2; k <= 64; k <<= 1) {
            for (int j = k >> 1; j > 0; j >>= 1) {
                unsigned long long o = __shfl_xor(val, j);
                bool takeMin = ((l & k) == 0) == ((l & j) == 0);
                unsigned long long mn = (o < val) ? o : val;
                unsigned long long mx = (o < val) ? val : o;
                val = takeMin ? mn : mx;
            }
        }
        if (l < m) incsr[rs + l] = (unsigned short)(val & 0xFFFULL);
        if (l == 0) rl[v] = m | (selfAny ? 0x10000 : 0);
    } else if (l == 0) {
        // fallback (not expected for this input): sequential filter + insertion
        int w = rs;
        bool selfAny = false;
        for (int e = rs; e < rs + deg; ++e) {
            int u = (int)incsr[e];
            if (u == v) { selfAny = true; continue; }
            unsigned mu = key[u];
            if (!(mu > mv || (mu == mv && u < v))) continue;
            int j = w;
            while (j > rs) {
                int q = (int)incsr[j - 1];
                unsigned mq = key[q];
                if (mu > mq || (mu == mq && u < q)) { incsr[j] = (unsigned short)q; --j; }
                else break;
            }
            incsr[j] = (unsigned short)u; ++w;
        }
        rl[v] = (w - rs) | (selfAny ? 0x10000 : 0);
    }
}

// ---- K34: 1-CU spin front-chase fixpoint on pre-sorted rows (47us proven) ----
// 16 waves, 4 nodes/thread. Sorted rows: front = min live key; front center =>
// absorb (== verified mC<minU rule); absorbed fronts skipped exactly once;
// exhausted => center. Polls are 1 u8 LDS read; hot nodes broadcast.
// r7/r9/r10 lesson: rank-chunk single-wave variants are latency-naked (103-186us);
// the multi-wave spin hides the same LDS latencies behind 64 waves of TLP.
__global__ void __launch_bounds__(1024) k34_fix(
        const int* __restrict__ rowst, const int* __restrict__ rl,
        const unsigned short* __restrict__ incsr_g,
        int* __restrict__ map_g, int* __restrict__ rem_g, int* __restrict__ relab_g,
        int* __restrict__ perm_a, int* __restrict__ nkeep_g) {
    __shared__ __align__(16) char buf[135232];
    unsigned short* incsr = (unsigned short*)buf;                        // 128K
    volatile unsigned char* stat = (volatile unsigned char*)(buf + 131072);  // 4K
    int* wt = (int*)(buf + 135168);
    int tid = threadIdx.x, lane = tid & 63, wv = tid >> 6;

    for (int i = tid; i < 131072 / 16; i += 1024)
        ((int4*)incsr)[i] = ((const int4*)incsr_g)[i];
    ((int*)(buf + 131072))[tid] = 0;
    int4 rsq = ((const int4*)rowst)[tid];
    int4 rlq = ((const int4*)rl)[tid];
    int rs4[4] = {rsq.x, rsq.y, rsq.z, rsq.w};
    int rq4[4] = {rlq.x, rlq.y, rlq.z, rlq.w};
    __syncthreads();

    unsigned resolved = 0, centerm = 0, selfm = 0;
    int pos4[4], re4[4], fu4[4] = {0, 0, 0, 0};
    #pragma unroll
    for (int t = 0; t < 4; ++t) {
        int v = 4 * tid + t;
        int m = rq4[t] & 0xFFFF;
        if (rq4[t] & 0x10000) selfm |= 1u << t;
        int lo = rs4[t];
        pos4[t] = lo; re4[t] = lo + m;
        if (m == 0) {                                    // no earlier in-nbrs: center
            map_g[v] = v; stat[v] = 1;
            centerm |= 1u << t; resolved |= 1u << t;
        } else {
            fu4[t] = (int)incsr[lo];
        }
    }

    int guard = 0;
    while (resolved != 0xFu && guard < 1000000) {
        ++guard;
        bool prog = false;
        #pragma unroll
        for (int t = 0; t < 4; ++t) {
            if (resolved & (1u << t)) continue;
            int v = 4 * tid + t;
            int u = fu4[t];
            int st = (int)stat[u];
            if (st == 0) continue;                       // front unresolved: blocked
            prog = true;
            if (st == 1) {                               // front is center: absorbed
                map_g[v] = u; stat[v] = 2; resolved |= 1u << t; continue;
            }
            int p = pos4[t] + 1, hi = re4[t];            // front absorbed: advance
            bool done = false;
            while (p < hi) {
                u = (int)incsr[p];
                st = (int)stat[u];
                if (st == 2) { ++p; continue; }
                if (st == 1) {
                    map_g[v] = u; stat[v] = 2; resolved |= 1u << t; done = true;
                }
                break;                                   // st==0: blocked here
            }
            if (!done) {
                if (p >= hi) {                           // all earlier absorbed: center
                    map_g[v] = v; stat[v] = 1; centerm |= 1u << t; resolved |= 1u << t;
                } else {
                    pos4[t] = p; fu4[t] = u;
                }
            }
        }
        if (__ballot(prog) == 0) __builtin_amdgcn_s_sleep(1);
    }
    __syncthreads();

    // relabel prefix + perm + globals
    int remb[4], cnt4 = 0;
    #pragma unroll
    for (int t = 0; t < 4; ++t) {
        remb[t] = ((centerm >> t) & 1) && !((selfm >> t) & 1);
        cnt4 += remb[t];
    }
    int inc2 = cnt4;
    for (int off = 1; off < 64; off <<= 1) {
        int v = __shfl_up(inc2, off);
        if (lane >= off) inc2 += v;
    }
    if (lane == 63) wt[wv] = inc2;
    __syncthreads();
    if (wv == 0 && lane < 16) {
        int v = wt[lane];
        for (int off = 1; off < 16; off <<= 1) {
            int u2 = __shfl_up(v, off);
            if (lane >= off) v += u2;
        }
        wt[lane] = v;
    }
    __syncthreads();
    int woff2 = (wv > 0) ? wt[wv - 1] : 0;
    int run = woff2 + inc2 - cnt4;
    #pragma unroll
    for (int t = 0; t < 4; ++t) {
        int v = 4 * tid + t;
        relab_g[v] = run;
        if (remb[t]) { perm_a[run] = v; ++run; }
        rem_g[v] = remb[t];
    }
    if (tid == 1023) nkeep_g[0] = run;
}

// ---------------- K56: all outputs; x region is pure atomic-add over zeroed base ----
__global__ void k56_outputs(const float* __restrict__ x, const int* __restrict__ map_g,
                            const int* __restrict__ rem_g, const int* __restrict__ relab_g,
                            const int* __restrict__ perm_a, const int* __restrict__ ei,
                            const int* __restrict__ batch, const int* __restrict__ nkeep_g,
                            float* __restrict__ out) {
    int idx = blockIdx.x * blockDim.x + threadIdx.x;
    if (idx < NN * ND) {
        int n = idx >> 6, d = idx & 63;
        int m = map_g[n];                 // m==n for centers & kept free nodes
        if (rem_g[m]) atomicAdd(&out[relab_g[m] * ND + d], x[idx]);
    } else if (idx < NN * ND + 2 * NE) {
        int e = idx - NN * ND;
        int row = e >> 16;                // NE == 1<<16
        int ee = e & (NE - 1);
        int s = ei[ee], t = ei[NE + ee];
        bool valid = (rem_g[s] != 0) && (rem_g[t] != 0);
        int endp = (row == 0) ? s : t;
        out[idx] = valid ? (float)relab_g[endp] : -1.0f;
    } else if (idx < NN * ND + 2 * NE + NN) {
        int r = idx - (NN * ND + 2 * NE);
        int nk = nkeep_g[0];
        out[idx] = (r < nk) ? (float)batch[perm_a[r]] : -1.0f;
    } else if (idx < NN * ND + 2 * NE + 2 * NN) {
        int r = idx - (NN * ND + 2 * NE + NN);
        int nk = nkeep_g[0];
        out[idx] = (r < nk) ? (float)perm_a[r] : -1.0f;
    }
}

extern "C" void kernel_launch(void* const* d_in, const int* in_sizes, int n_in,
                              void* d_out, int out_size, void* d_ws, size_t ws_size,
                              hipStream_t stream) {
    const float* x     = (const float*)d_in[0];
    const int*   ei    = (const int*)d_in[1];
    const int*   batch = (const int*)d_in[2];
    const float* wrel  = (const float*)d_in[3];
    const float* wroot = (const float*)d_in[4];
    const float* b     = (const float*)d_in[5];

    char* ws = (char*)d_ws;
    int*    map_g  = (int*)(ws + 0);
    int*    rem_g  = (int*)(ws + 16384);
    int*    relab  = (int*)(ws + 32768);
    int*    perma  = (int*)(ws + 49152);
    int*    nkeep  = (int*)(ws + 65536);
    int*    rl     = (int*)(ws + 65600);
    int*    rowst  = (int*)(ws + 81984);
    unsigned* key  = (unsigned*)(ws + 98432);
    unsigned short* incsr = (unsigned short*)(ws + 114816);

    float* out = (float*)d_out;

    kB_csr<<<1, 1024, 0, stream>>>(ei, incsr, rowst);
    kX_keys<<<1024, 256, 0, stream>>>(x, wrel, wroot, b, rowst, incsr, key);
    k5_filtersort<<<1024, 256, 0, stream>>>(rowst, key, incsr, rl, out);
    k34_fix<<<1, 1024, 0, stream>>>(rowst, rl, incsr, map_g, rem_g, relab, perma, nkeep);
    int total_out = NN * ND + 2 * NE + 2 * NN;  // 401408
    k56_outputs<<<(total_out + 255) / 256, 256, 0, stream>>>(x, map_g, rem_g, relab,
                                                             perma, ei, batch, nkeep, out);
}

// Round 13
// 139.526 us; speedup vs baseline: 1.0044x; 1.0044x over previous
//
#include <hip/hip_runtime.h>

#define NN 4096
#define NE 65536
#define ND 64

// ---------- workspace layout (bytes) ----------
// 0      : map    i32[NN]
// 16384  : rem    i32[NN]
// 32768  : relab  i32[NN]
// 49152  : perma  i32[NN]
// 65536  : nkeep  i32
// 65600  : rl     i32[NN]   (len | self<<16, K5)
// 81984  : rowst  i32[NN+1]
// 98432  : key    u32[NN]
// 114816 : rank   i32[NN]   (K5 side job)
// 131200 : incsr  u16[NE]   (128K; KB builds, K5 sorts rows in place)

// ---- KB: CSR build on ONE block (count+scan+scatter in LDS, coalesced dump) ----
__global__ void __launch_bounds__(1024) kB_csr(const int* __restrict__ ei,
                                               unsigned short* __restrict__ incsr_g,
                                               int* __restrict__ rowst_g) {
    __shared__ __align__(16) char buf[147520];
    unsigned short* incsr = (unsigned short*)buf;          // 128K
    int* cursor = (int*)(buf + 131072);                    // 16K
    int* wt = (int*)(buf + 147456);                        // 64B
    int tid = threadIdx.x, lane = tid & 63, wv = tid >> 6;

    for (int n = tid; n < NN; n += 1024) cursor[n] = 0;
    __syncthreads();
    const int4* eid4 = (const int4*)(ei + NE);
    for (int i = tid; i < NE / 4; i += 1024) {
        int4 q = eid4[i];
        atomicAdd(&cursor[q.x], 1);
        atomicAdd(&cursor[q.y], 1);
        atomicAdd(&cursor[q.z], 1);
        atomicAdd(&cursor[q.w], 1);
    }
    __syncthreads();

    int t0 = cursor[4 * tid], t1 = cursor[4 * tid + 1];
    int t2 = cursor[4 * tid + 2], t3 = cursor[4 * tid + 3];
    int tot = t0 + t1 + t2 + t3;
    int inc = tot;
    for (int off = 1; off < 64; off <<= 1) {
        int v = __shfl_up(inc, off);
        if (lane >= off) inc += v;
    }
    if (lane == 63) wt[wv] = inc;
    __syncthreads();
    if (wv == 0 && lane < 16) {
        int v = wt[lane];
        for (int off = 1; off < 16; off <<= 1) {
            int u2 = __shfl_up(v, off);
            if (lane >= off) v += u2;
        }
        wt[lane] = v;
    }
    __syncthreads();
    int waveoff = (wv > 0) ? wt[wv - 1] : 0;
    int excl = waveoff + inc - tot;
    int4 rsv;
    rsv.x = excl; rsv.y = excl + t0; rsv.z = excl + t0 + t1; rsv.w = excl + t0 + t1 + t2;
    ((int4*)rowst_g)[tid] = rsv;
    if (tid == 1023) rowst_g[NN] = NE;
    cursor[4 * tid]     = rsv.x;
    cursor[4 * tid + 1] = rsv.y;
    cursor[4 * tid + 2] = rsv.z;
    cursor[4 * tid + 3] = rsv.w;
    __syncthreads();

    const int4* eis4 = (const int4*)ei;
    for (int i = tid; i < NE / 4; i += 1024) {
        int4 s = eis4[i];
        int4 d = eid4[i];
        incsr[atomicAdd(&cursor[d.x], 1)] = (unsigned short)s.x;
        incsr[atomicAdd(&cursor[d.y], 1)] = (unsigned short)s.y;
        incsr[atomicAdd(&cursor[d.z], 1)] = (unsigned short)s.z;
        incsr[atomicAdd(&cursor[d.w], 1)] = (unsigned short)s.w;
    }
    __syncthreads();

    for (int i = tid; i < 8192; i += 1024)
        ((int4*)incsr_g)[i] = ((const int4*)incsr)[i];
}

// ---- KX: fused dots+agg+key, one wave per row ----
__global__ void kX_keys(const float* __restrict__ x, const float* __restrict__ wrel,
                        const float* __restrict__ wroot, const float* __restrict__ bptr,
                        const int* __restrict__ rowst, const unsigned short* __restrict__ incsr,
                        unsigned* __restrict__ key) {
    int gt = blockIdx.x * blockDim.x + threadIdx.x;
    int v = gt >> 6, lane = gt & 63;
    int rs = rowst[v], deg = rowst[v + 1] - rs;
    double acc = 0.0;
    for (int base = 0; base < deg; base += 64) {
        int n = deg - base; if (n > 64) n = 64;
        int ent = (lane < n) ? (int)incsr[rs + base + lane] : 0;
        for (int e = 0; e < n; ++e) {
            int u = __shfl(ent, e);
            acc += (double)x[(u << 6) | lane];
        }
    }
    double red = acc * (double)wrel[lane]
               + (double)x[(v << 6) | lane] * (double)wroot[lane];
    for (int off = 32; off > 0; off >>= 1) red += __shfl_down(red, off);
    if (lane == 0) {
        float sc = tanhf((float)(red + (double)bptr[0]));   // f32 saturation => ref ties
        unsigned m = __float_as_uint(sc);
        m = (m & 0x80000000u) ? ~m : (m | 0x80000000u);     // monotone ascending in score
        key[v] = m;
    }
}

// ------- K5: per-row filter + 64-lane bitonic sort; side jobs: out-zero + rank -------
// Rank job is the r9/r10 per-wave form (proven cheap): each lane count-compares 64
// keys via 16 uint4 L1/L2-hot loads, shuffle-reduce, single store.
__global__ void k5_filtersort(const int* __restrict__ rowst, const unsigned* __restrict__ key,
                              unsigned short* __restrict__ incsr, int* __restrict__ rl,
                              int* __restrict__ rank_g, float* __restrict__ out) {
    int g = blockIdx.x * blockDim.x + threadIdx.x;
    if (g < (NN * ND) / 4) ((float4*)out)[g] = make_float4(0.f, 0.f, 0.f, 0.f);

    int v = g >> 6, l = g & 63;
    int rs = rowst[v], deg = rowst[v + 1] - rs;
    unsigned mv = key[v];
    if (deg <= 64) {
        int u = (l < deg) ? (int)incsr[rs + l] : -1;
        bool isself = (l < deg) && (u == v);
        unsigned mu = (l < deg && !isself) ? key[u] : 0u;
        bool keep = (l < deg) && !isself && (mu > mv || (mu == mv && u < v));
        unsigned long long val = keep
            ? ((((unsigned long long)(~mu)) << 12) | (unsigned)u) : ~0ULL;
        int m = __popcll(__ballot(keep));
        bool selfAny = __ballot(isself) != 0ULL;
        for (int k = 2; k <= 64; k <<= 1) {
            for (int j = k >> 1; j > 0; j >>= 1) {
                unsigned long long o = __shfl_xor(val, j);
                bool takeMin = ((l & k) == 0) == ((l & j) == 0);
                unsigned long long mn = (o < val) ? o : val;
                unsigned long long mx = (o < val) ? val : o;
                val = takeMin ? mn : mx;
            }
        }
        if (l < m) incsr[rs + l] = (unsigned short)(val & 0xFFFULL);
        if (l == 0) rl[v] = m | (selfAny ? 0x10000 : 0);
    } else if (l == 0) {
        int w = rs;
        bool selfAny = false;
        for (int e = rs; e < rs + deg; ++e) {
            int u = (int)incsr[e];
            if (u == v) { selfAny = true; continue; }
            unsigned mu = key[u];
            if (!(mu > mv || (mu == mv && u < v))) continue;
            int j = w;
            while (j > rs) {
                int q = (int)incsr[j - 1];
                unsigned mq = key[q];
                if (mu > mq || (mu == mq && u < q)) { incsr[j] = (unsigned short)q; --j; }
                else break;
            }
            incsr[j] = (unsigned short)u; ++w;
        }
        rl[v] = (w - rs) | (selfAny ? 0x10000 : 0);
    }

    // side job: rank[v] = #{u : key_u>key_v || (key_u==key_v && u<v)}
    {
        int cntk = 0;
        const uint4* k4p = (const uint4*)key;
        #pragma unroll 4
        for (int i = 0; i < 16; ++i) {
            uint4 kq = k4p[(l << 4) | i];
            int u0 = (l << 6) | (i << 2);
            cntk += (kq.x > mv || (kq.x == mv && (u0    ) < v));
            cntk += (kq.y > mv || (kq.y == mv && (u0 + 1) < v));
            cntk += (kq.z > mv || (kq.z == mv && (u0 + 2) < v));
            cntk += (kq.w > mv || (kq.w == mv && (u0 + 3) < v));
        }
        for (int off = 32; off > 0; off >>= 1) cntk += __shfl_down(cntk, off);
        if (l == 0) rank_g[v] = cntk;
    }
}

// ---- K34: spin front-chase with RANK-ORDERED node->thread assignment ----
// Proven spin semantics (r4/r11, 47us) unchanged; only the assignment permutes:
// thread tid hosts the nodes of ranks 4tid..4tid+3 (deps point to lower ranks).
// Mechanism: waves drain monotonically (wave w exits once its rank window is
// done) => frontier wave competes with ever-fewer waves; a blocked node's front
// is usually in the same/adjacent wave => shorter hop latency. Permutation-
// invariant semantics => zero correctness risk. Tail reads stat/lsf by NODE.
__global__ void __launch_bounds__(1024) k34_fix(
        const int* __restrict__ rowst, const int* __restrict__ rl,
        const unsigned short* __restrict__ incsr_g, const int* __restrict__ rank_g,
        int* __restrict__ map_g, int* __restrict__ rem_g, int* __restrict__ relab_g,
        int* __restrict__ perm_a, int* __restrict__ nkeep_g) {
    __shared__ __align__(16) char buf[155776];
    unsigned short* incsr = (unsigned short*)buf;                        // 128K
    volatile unsigned char* stat = (volatile unsigned char*)(buf + 131072); // 4K
    unsigned short* r2n = (unsigned short*)(buf + 135168);               // 8K rank->node
    unsigned short* rst = (unsigned short*)(buf + 143360);               // 8K node->start
    unsigned char*  lsf = (unsigned char*)(buf + 151552);                // 4K len|self<<7
    int* wt = (int*)(buf + 155648);
    int tid = threadIdx.x, lane = tid & 63, wv = tid >> 6;

    for (int i = tid; i < 131072 / 16; i += 1024)
        ((int4*)incsr)[i] = ((const int4*)incsr_g)[i];
    ((int*)(buf + 131072))[tid] = 0;                                     // stat = 0
    int4 rsq = ((const int4*)rowst)[tid];
    int4 rlq = ((const int4*)rl)[tid];
    int4 rkq = ((const int4*)rank_g)[tid];
    int rs4s[4] = {rsq.x, rsq.y, rsq.z, rsq.w};
    int rq4s[4] = {rlq.x, rlq.y, rlq.z, rlq.w};
    int rk4s[4] = {rkq.x, rkq.y, rkq.z, rkq.w};
    #pragma unroll
    for (int t = 0; t < 4; ++t) {
        int v = 4 * tid + t;
        rst[v] = (unsigned short)rs4s[t];    // start<=65535 whenever len>0 (else unused)
        lsf[v] = (unsigned char)((rq4s[t] & 0x7F) | ((rq4s[t] & 0x10000) ? 0x80 : 0));
        r2n[rk4s[t]] = (unsigned short)v;    // rank is a permutation of 0..NN-1
    }
    __syncthreads();

    unsigned resolved = 0;
    int pos4[4], re4[4], fu4[4] = {0, 0, 0, 0}, vr4[4];
    #pragma unroll
    for (int t = 0; t < 4; ++t) {
        int v = (int)r2n[4 * tid + t];       // node of rank 4*tid+t
        vr4[t] = v;
        int lo = (int)rst[v];
        int m = lsf[v] & 0x7F;
        pos4[t] = lo; re4[t] = lo + m;
        if (m == 0) {                        // no earlier in-nbrs: center
            map_g[v] = v; stat[v] = 1;
            resolved |= 1u << t;
        } else {
            fu4[t] = (int)incsr[lo];
        }
    }

    int guard = 0;
    while (resolved != 0xFu && guard < 1000000) {
        ++guard;
        bool prog = false;
        #pragma unroll
        for (int t = 0; t < 4; ++t) {
            if (resolved & (1u << t)) continue;
            int v = vr4[t];
            int u = fu4[t];
            int st = (int)stat[u];
            if (st == 0) continue;                       // front unresolved: blocked
            prog = true;
            if (st == 1) {                               // front is center: absorbed
                map_g[v] = u; stat[v] = 2; resolved |= 1u << t; continue;
            }
            int p = pos4[t] + 1, hi = re4[t];            // front absorbed: advance
            bool done = false;
            while (p < hi) {
                u = (int)incsr[p];
                st = (int)stat[u];
                if (st == 2) { ++p; continue; }
                if (st == 1) {
                    map_g[v] = u; stat[v] = 2; resolved |= 1u << t; done = true;
                }
                break;                                   // st==0: blocked here
            }
            if (!done) {
                if (p >= hi) {                           // all earlier absorbed: center
                    map_g[v] = v; stat[v] = 1; resolved |= 1u << t;
                } else {
                    pos4[t] = p; fu4[t] = u;
                }
            }
        }
        if (__ballot(prog) == 0) __builtin_amdgcn_s_sleep(1);
    }
    __syncthreads();

    // relabel prefix + perm + globals (node order, from LDS stat/lsf)
    int remb[4], cnt4 = 0;
    #pragma unroll
    for (int t = 0; t < 4; ++t) {
        int v = 4 * tid + t;
        remb[t] = (stat[v] == 1) && !(lsf[v] & 0x80);
        cnt4 += remb[t];
    }
    int inc2 = cnt4;
    for (int off = 1; off < 64; off <<= 1) {
        int v = __shfl_up(inc2, off);
        if (lane >= off) inc2 += v;
    }
    if (lane == 63) wt[wv] = inc2;
    __syncthreads();
    if (wv == 0 && lane < 16) {
        int v = wt[lane];
        for (int off = 1; off < 16; off <<= 1) {
            int u2 = __shfl_up(v, off);
            if (lane >= off) v += u2;
        }
        wt[lane] = v;
    }
    __syncthreads();
    int woff2 = (wv > 0) ? wt[wv - 1] : 0;
    int run = woff2 + inc2 - cnt4;
    #pragma unroll
    for (int t = 0; t < 4; ++t) {
        int v = 4 * tid + t;
        relab_g[v] = run;
        if (remb[t]) { perm_a[run] = v; ++run; }
        rem_g[v] = remb[t];
    }
    if (tid == 1023) nkeep_g[0] = run;
}

// ---------------- K56: all outputs; x region is pure atomic-add over zeroed base ----
__global__ void k56_outputs(const float* __restrict__ x, const int* __restrict__ map_g,
                            const int* __restrict__ rem_g, const int* __restrict__ relab_g,
                            const int* __restrict__ perm_a, const int* __restrict__ ei,
                            const int* __restrict__ batch, const int* __restrict__ nkeep_g,
                            float* __restrict__ out) {
    int idx = blockIdx.x * blockDim.x + threadIdx.x;
    if (idx < NN * ND) {
        int n = idx >> 6, d = idx & 63;
        int m = map_g[n];
        if (rem_g[m]) atomicAdd(&out[relab_g[m] * ND + d], x[idx]);
    } else if (idx < NN * ND + 2 * NE) {
        int e = idx - NN * ND;
        int row = e >> 16;
        int ee = e & (NE - 1);
        int s = ei[ee], t = ei[NE + ee];
        bool valid = (rem_g[s] != 0) && (rem_g[t] != 0);
        int endp = (row == 0) ? s : t;
        out[idx] = valid ? (float)relab_g[endp] : -1.0f;
    } else if (idx < NN * ND + 2 * NE + NN) {
        int r = idx - (NN * ND + 2 * NE);
        int nk = nkeep_g[0];
        out[idx] = (r < nk) ? (float)batch[perm_a[r]] : -1.0f;
    } else if (idx < NN * ND + 2 * NE + 2 * NN) {
        int r = idx - (NN * ND + 2 * NE + NN);
        int nk = nkeep_g[0];
        out[idx] = (r < nk) ? (float)perm_a[r] : -1.0f;
    }
}

extern "C" void kernel_launch(void* const* d_in, const int* in_sizes, int n_in,
                              void* d_out, int out_size, void* d_ws, size_t ws_size,
                              hipStream_t stream) {
    const float* x     = (const float*)d_in[0];
    const int*   ei    = (const int*)d_in[1];
    const int*   batch = (const int*)d_in[2];
    const float* wrel  = (const float*)d_in[3];
    const float* wroot = (const float*)d_in[4];
    const float* b     = (const float*)d_in[5];

    char* ws = (char*)d_ws;
    int*    map_g  = (int*)(ws + 0);
    int*    rem_g  = (int*)(ws + 16384);
    int*    relab  = (int*)(ws + 32768);
    int*    perma  = (int*)(ws + 49152);
    int*    nkeep  = (int*)(ws + 65536);
    int*    rl     = (int*)(ws + 65600);
    int*    rowst  = (int*)(ws + 81984);
    unsigned* key  = (unsigned*)(ws + 98432);
    int*    rankp  = (int*)(ws + 114816);
    unsigned short* incsr = (unsigned short*)(ws + 131200);

    float* out = (float*)d_out;

    kB_csr<<<1, 1024, 0, stream>>>(ei, incsr, rowst);
    kX_keys<<<1024, 256, 0, stream>>>(x, wrel, wroot, b, rowst, incsr, key);
    k5_filtersort<<<1024, 256, 0, stream>>>(rowst, key, incsr, rl, rankp, out);
    k34_fix<<<1, 1024, 0, stream>>>(rowst, rl, incsr, rankp, map_g, rem_g, relab,
                                    perma, nkeep);
    int total_out = NN * ND + 2 * NE + 2 * NN;  // 401408
    k56_outputs<<<(total_out + 255) / 256, 256, 0, stream>>>(x, map_g, rem_g, relab,
                                                             perma, ei, batch, nkeep, out);
}